// Round 4
// baseline (124.030 us; speedup 1.0000x reference)
//
#include <hip/hip_runtime.h>
#include <hip/hip_bf16.h>

// GaussSpatialConv: out[i,:] = softmax_j(-||x_i-y_j||^2 * 50) @ y_fea
// B=1, N=M=12288, D=16, fp32.
//
// R4: pk-f32 math (v_pk_fma_f32) for logits/max, s-sum via second MFMA with
// B=ones (kills serial add chain), kacc occupancy (512-thr blocks, CH=32,
// 18 KB LDS), coalesced kprep, merged memsets.

#define NROWS 12288
#define MCOLS 12288
#define DFEA  16
#define CC 72.13475204444817f   // 50 * log2(e)

typedef __attribute__((ext_vector_type(8))) short bf16x8;
typedef __attribute__((ext_vector_type(4))) float f32x4;
typedef __attribute__((ext_vector_type(2))) float f32x2;

#if __has_builtin(__builtin_amdgcn_exp2f)
#define EXP2(x) __builtin_amdgcn_exp2f(x)
#else
#define EXP2(x) exp2f(x)
#endif

__device__ __forceinline__ f32x2 sp2(float v) { return (f32x2){v, v}; }
__device__ __forceinline__ f32x2 fma2(f32x2 a, f32x2 b, f32x2 c) {
    return __builtin_elementwise_fma(a, b, c);
}
__device__ __forceinline__ f32x2 max2(f32x2 a, f32x2 b) {
    return __builtin_elementwise_max(a, b);
}

// monotone float<->uint map for atomicMax over signed floats
__device__ __forceinline__ unsigned enc_f(float f) {
    unsigned u = __float_as_uint(f);
    return u ^ ((unsigned)((int)u >> 31) | 0x80000000u);
}
__device__ __forceinline__ float dec_f(unsigned u) {
    unsigned b = (u & 0x80000000u) ? (u ^ 0x80000000u) : ~u;
    return __uint_as_float(b);
}

__device__ __forceinline__ unsigned pk_bf16(float a, float b) {
    __hip_bfloat162 h = __float22bfloat162_rn(make_float2(a, b));
    unsigned u; __builtin_memcpy(&u, &h, 4); return u;
}

// ws float layout: G [0,N) u32 | ssum [N,2N) | y4 [2N,6N) float4 | feaB [6N,14N) uint4

// ---------------------------------------------------------------- kprep ----
// blocks 0..47: y4 = {2CC*y, -CC*|y|^2}. blocks 48..143: feaB b-frag repack
// (coalesced via LDS: 128 j-rows per block).
__global__ __launch_bounds__(256) void kprep_kernel(const float* __restrict__ y,
                                                    const float* __restrict__ fea,
                                                    float4* __restrict__ y4,
                                                    uint4* __restrict__ feaB) {
    __shared__ float fs[128 * DFEA];   // 8 KB
    int b = blockIdx.x, t = threadIdx.x;
    if (b < 48) {
        int i = b * 256 + t;
        float a = y[3 * i + 0], c = y[3 * i + 1], d = y[3 * i + 2];
        y4[i] = make_float4(2.0f * CC * a, 2.0f * CC * c, 2.0f * CC * d,
                            -CC * (a * a + c * c + d * d));
    } else {
        int blk2 = b - 48;             // 0..95
        int j0 = blk2 * 128;
        const float4* src = (const float4*)(fea + (size_t)j0 * DFEA);
        float4* dst = (float4*)fs;
        dst[t] = src[t];
        dst[t + 256] = src[t + 256];
        __syncthreads();
        int tile = t >> 6, lane = t & 63;
        int jb = tile * 32 + ((lane >> 4) << 3);
        int col = lane & 15;
        float v[8];
        #pragma unroll
        for (int jj = 0; jj < 8; ++jj) v[jj] = fs[(jb + jj) * DFEA + col];
        uint4 o;
        o.x = pk_bf16(v[0], v[1]); o.y = pk_bf16(v[2], v[3]);
        o.z = pk_bf16(v[4], v[5]); o.w = pk_bf16(v[6], v[7]);
        feaB[blk2 * 256 + t] = o;
    }
}

// ---------------------------------------------------------------- kmax ----
// 768 blocks: rb = b>>7 (6 row-blocks of 2048), jc = b&127 (96 j's each)
__global__ __launch_bounds__(256) void kmax_kernel(const float* __restrict__ x,
                                                   const float4* __restrict__ y4,
                                                   unsigned* __restrict__ G) {
    __shared__ float s0[96], s1[96], s2[96], sw[96];
    int t  = threadIdx.x;
    int rb = blockIdx.x >> 7;
    int jc = blockIdx.x & 127;
    int j0 = jc * 96;
    if (t < 96) {
        float4 v = y4[j0 + t];
        s0[t] = v.x; s1[t] = v.y; s2[t] = v.z; sw[t] = v.w;
    }
    __syncthreads();

    int wv   = t >> 6;
    int lane = t & 63;
    int r0   = rb * 2048 + wv * 512 + lane;   // rows r0 + 64k

    float X0[8], X1[8], X2[8];
    f32x2 mk[8];
    #pragma unroll
    for (int k = 0; k < 8; ++k) {
        int row = r0 + 64 * k;
        X0[k] = x[3 * row + 0]; X1[k] = x[3 * row + 1]; X2[k] = x[3 * row + 2];
        mk[k] = sp2(-3.4e38f);
    }

    for (int jj = 0; jj < 96; jj += 4) {
        f32x4 a0 = *(const f32x4*)&s0[jj];
        f32x4 a1 = *(const f32x4*)&s1[jj];
        f32x4 a2 = *(const f32x4*)&s2[jj];
        f32x4 aw = *(const f32x4*)&sw[jj];
        #pragma unroll
        for (int k = 0; k < 8; ++k) {
            f32x2 g = fma2(sp2(X2[k]), a2.xy, aw.xy);
            g = fma2(sp2(X1[k]), a1.xy, g);
            g = fma2(sp2(X0[k]), a0.xy, g);
            mk[k] = max2(mk[k], g);
            f32x2 h = fma2(sp2(X2[k]), a2.zw, aw.zw);
            h = fma2(sp2(X1[k]), a1.zw, h);
            h = fma2(sp2(X0[k]), a0.zw, h);
            mk[k] = max2(mk[k], h);
        }
    }
    #pragma unroll
    for (int k = 0; k < 8; ++k)
        atomicMax(G + r0 + 64 * k, enc_f(fmaxf(mk[k].x, mk[k].y)));
}

// ---------------------------------------------------------------- kacc ----
// 768 blocks x 512 threads: rb = b>>5 (24 row-blocks of 512 rows),
// jc = b&31 (384 j's each = 12 MFMA k-tiles).
__global__ __launch_bounds__(512) void kacc_kernel(const float* __restrict__ x,
                                                   const float4* __restrict__ y4,
                                                   const uint4* __restrict__ feaB,
                                                   const unsigned* __restrict__ G,
                                                   float* __restrict__ ssum,
                                                   float* __restrict__ out) {
    __shared__ float Ys0[384], Ys1[384], Ys2[384], Ysw[384];  // 6 KB SoA
    __shared__ uint4 Fb[768];                                 // 12 KB b-frags
    int t  = threadIdx.x;
    int rb = blockIdx.x >> 5;
    int jc = blockIdx.x & 31;
    int j0 = jc * 384;

    if (t < 384) {
        float4 v = y4[j0 + t];
        Ys0[t] = v.x; Ys1[t] = v.y; Ys2[t] = v.z; Ysw[t] = v.w;
    }
    {
        const uint4* fsrc = feaB + (j0 >> 5) * 64;
        for (int i = t; i < 768; i += 512) Fb[i] = fsrc[i];
    }
    __syncthreads();

    int wv   = t >> 6;
    int lane = t & 63;
    int grp  = lane >> 4;
    int m    = lane & 15;
    int rowbase = rb * 512 + wv * 64;

    float X0[4], X1[4], X2[4];
    f32x2 Gm2[4];
    #pragma unroll
    for (int r = 0; r < 4; ++r) {
        int row = rowbase + r * 16 + m;
        X0[r] = x[3 * row + 0]; X1[r] = x[3 * row + 1]; X2[r] = x[3 * row + 2];
        Gm2[r] = sp2(dec_f(G[row]));
    }

    const bf16x8 ones = (bf16x8){(short)0x3F80, (short)0x3F80, (short)0x3F80, (short)0x3F80,
                                 (short)0x3F80, (short)0x3F80, (short)0x3F80, (short)0x3F80};
    f32x4 acc[4], accs[4];
    #pragma unroll
    for (int r = 0; r < 4; ++r) {
        acc[r]  = (f32x4){0.f, 0.f, 0.f, 0.f};
        accs[r] = (f32x4){0.f, 0.f, 0.f, 0.f};
    }

    for (int kt = 0; kt < 12; ++kt) {
        int jb = kt * 32 + grp * 8;   // this lane's 8 k-positions
        f32x4 A0 = *(const f32x4*)&Ys0[jb], B0 = *(const f32x4*)&Ys0[jb + 4];
        f32x4 A1 = *(const f32x4*)&Ys1[jb], B1 = *(const f32x4*)&Ys1[jb + 4];
        f32x4 A2 = *(const f32x4*)&Ys2[jb], B2 = *(const f32x4*)&Ys2[jb + 4];
        f32x4 Aw = *(const f32x4*)&Ysw[jb], Bw = *(const f32x4*)&Ysw[jb + 4];
        bf16x8 bfrag = __builtin_bit_cast(bf16x8, Fb[kt * 64 + lane]);

        #pragma unroll
        for (int r = 0; r < 4; ++r) {
            f32x2 x0 = sp2(X0[r]), x1 = sp2(X1[r]), x2 = sp2(X2[r]);
            f32x2 g0 = fma2(x0, A0.xy, fma2(x1, A1.xy, fma2(x2, A2.xy, Aw.xy))) - Gm2[r];
            f32x2 g1 = fma2(x0, A0.zw, fma2(x1, A1.zw, fma2(x2, A2.zw, Aw.zw))) - Gm2[r];
            f32x2 g2 = fma2(x0, B0.xy, fma2(x1, B1.xy, fma2(x2, B2.xy, Bw.xy))) - Gm2[r];
            f32x2 g3 = fma2(x0, B0.zw, fma2(x1, B1.zw, fma2(x2, B2.zw, Bw.zw))) - Gm2[r];
            union { unsigned u[4]; bf16x8 v; } af;
            af.u[0] = pk_bf16(EXP2(g0.x), EXP2(g0.y));
            af.u[1] = pk_bf16(EXP2(g1.x), EXP2(g1.y));
            af.u[2] = pk_bf16(EXP2(g2.x), EXP2(g2.y));
            af.u[3] = pk_bf16(EXP2(g3.x), EXP2(g3.y));
            acc[r]  = __builtin_amdgcn_mfma_f32_16x16x32_bf16(af.v, bfrag, acc[r], 0, 0, 0);
            accs[r] = __builtin_amdgcn_mfma_f32_16x16x32_bf16(af.v, ones,  accs[r], 0, 0, 0);
        }
    }

    // epilogue. C/D layout: lane (grp,m) holds D[grp*4+reg][m].
    #pragma unroll
    for (int r = 0; r < 4; ++r) {
        #pragma unroll
        for (int reg = 0; reg < 4; ++reg) {
            int orow = rowbase + r * 16 + grp * 4 + reg;
            atomicAdd(out + (size_t)orow * DFEA + m, acc[r][reg]);
        }
        if (m == 0) {
            #pragma unroll
            for (int reg = 0; reg < 4; ++reg)
                atomicAdd(ssum + rowbase + r * 16 + grp * 4 + reg, accs[r][reg]);
        }
    }
}

// ---------------------------------------------------------------- kdiv ----
__global__ __launch_bounds__(256) void kdiv_kernel(float* __restrict__ out,
                                                   const float* __restrict__ ssum) {
    int t = blockIdx.x * 256 + threadIdx.x;
    out[t] = out[t] / ssum[t >> 4];   // s >= 1 (arg==0 at the argmax j)
}

// -------------------------------------------------------------- launch ----
extern "C" void kernel_launch(void* const* d_in, const int* in_sizes, int n_in,
                              void* d_out, int out_size, void* d_ws, size_t ws_size,
                              hipStream_t stream) {
    const float* x   = (const float*)d_in[0];   // [N,3]
    const float* y   = (const float*)d_in[1];   // [M,3]
    const float* fea = (const float*)d_in[2];   // [M,16]
    float* out = (float*)d_out;                 // [N,16]

    float*    wsf  = (float*)d_ws;
    unsigned* G    = (unsigned*)wsf;                        // N u32 (enc, 0 = -inf)
    float*    ssum = wsf + NROWS;                           // N f32
    float4*   y4   = (float4*)(wsf + 2 * NROWS);            // N float4
    uint4*    feaB = (uint4*)(wsf + 6 * NROWS);             // 2N uint4

    hipMemsetAsync((void*)G, 0, (size_t)2 * NROWS * 4, stream);  // G + ssum
    hipMemsetAsync(d_out, 0, (size_t)NROWS * DFEA * 4, stream);

    kprep_kernel<<<dim3(144), 256, 0, stream>>>(y, fea, y4, feaB);
    kmax_kernel<<<dim3(6 * 128), 256, 0, stream>>>(x, y4, G);
    kacc_kernel<<<dim3(24 * 32), 512, 0, stream>>>(x, y4, feaB, G, ssum, out);
    kdiv_kernel<<<dim3((NROWS * DFEA) / 256), 256, 0, stream>>>(out, ssum);
}

// Round 5
// 120.263 us; speedup vs baseline: 1.0313x; 1.0313x over previous
//
#include <hip/hip_runtime.h>
#include <hip/hip_bf16.h>

// GaussSpatialConv: out[i,:] = softmax_j(-||x_i-y_j||^2 * 50) @ y_fea
// B=1, N=M=12288, D=16, fp32.
//
// R5: occupancy + overhead round.
//  - kacc: 256-thr blocks, grid 1536 (6 blk/CU), Fb read direct from global
//    (L2-resident) instead of LDS -> 6 KB LDS, launch_bounds(256,4).
//  - kprep absorbs all zero-init (no hipMemsetAsync nodes; 4-node graph).
//  - kmax: jc=64 (atomics halved to 786k).

#define NROWS 12288
#define MCOLS 12288
#define DFEA  16
#define CC 72.13475204444817f   // 50 * log2(e)

typedef __attribute__((ext_vector_type(8))) short bf16x8;
typedef __attribute__((ext_vector_type(4))) float f32x4;
typedef __attribute__((ext_vector_type(2))) float f32x2;

#if __has_builtin(__builtin_amdgcn_exp2f)
#define EXP2(x) __builtin_amdgcn_exp2f(x)
#else
#define EXP2(x) exp2f(x)
#endif

__device__ __forceinline__ f32x2 sp2(float v) { return (f32x2){v, v}; }
__device__ __forceinline__ f32x2 fma2(f32x2 a, f32x2 b, f32x2 c) {
    return __builtin_elementwise_fma(a, b, c);
}
__device__ __forceinline__ f32x2 max2(f32x2 a, f32x2 b) {
    return __builtin_elementwise_max(a, b);
}

// monotone float<->uint map for atomicMax over signed floats
__device__ __forceinline__ unsigned enc_f(float f) {
    unsigned u = __float_as_uint(f);
    return u ^ ((unsigned)((int)u >> 31) | 0x80000000u);
}
__device__ __forceinline__ float dec_f(unsigned u) {
    unsigned b = (u & 0x80000000u) ? (u ^ 0x80000000u) : ~u;
    return __uint_as_float(b);
}

__device__ __forceinline__ unsigned pk_bf16(float a, float b) {
    __hip_bfloat162 h = __float22bfloat162_rn(make_float2(a, b));
    unsigned u; __builtin_memcpy(&u, &h, 4); return u;
}

// ws float layout: G [0,N) u32 | ssum [N,2N) | y4 [2N,6N) float4 | feaB [6N,14N) uint4

// ---------------------------------------------------------------- kprep ----
// 192 blocks: 0..47 y4 pack, 48..143 feaB b-frag repack, 144..191 zero-init
// of G / ssum / out (replaces memset nodes).
__global__ __launch_bounds__(256) void kprep_kernel(const float* __restrict__ y,
                                                    const float* __restrict__ fea,
                                                    float4* __restrict__ y4,
                                                    uint4* __restrict__ feaB,
                                                    unsigned* __restrict__ G,
                                                    float* __restrict__ ssum,
                                                    float* __restrict__ out) {
    __shared__ float fs[128 * DFEA];   // 8 KB
    int b = blockIdx.x, t = threadIdx.x;
    if (b < 48) {
        int i = b * 256 + t;
        float a = y[3 * i + 0], c = y[3 * i + 1], d = y[3 * i + 2];
        y4[i] = make_float4(2.0f * CC * a, 2.0f * CC * c, 2.0f * CC * d,
                            -CC * (a * a + c * c + d * d));
    } else if (b < 144) {
        int blk2 = b - 48;             // 0..95
        int j0 = blk2 * 128;
        const float4* src = (const float4*)(fea + (size_t)j0 * DFEA);
        float4* dst = (float4*)fs;
        dst[t] = src[t];
        dst[t + 256] = src[t + 256];
        __syncthreads();
        int tile = t >> 6, lane = t & 63;
        int jb = tile * 32 + ((lane >> 4) << 3);
        int col = lane & 15;
        float v[8];
        #pragma unroll
        for (int jj = 0; jj < 8; ++jj) v[jj] = fs[(jb + jj) * DFEA + col];
        uint4 o;
        o.x = pk_bf16(v[0], v[1]); o.y = pk_bf16(v[2], v[3]);
        o.z = pk_bf16(v[4], v[5]); o.w = pk_bf16(v[6], v[7]);
        feaB[blk2 * 256 + t] = o;
    } else {
        int i = (b - 144) * 256 + t;   // 0..12287
        G[i] = 0u;                     // enc(-inf)
        ssum[i] = 0.0f;
        float4* o4 = (float4*)out;     // 49152 float4, 4 per thread
        float4 z = make_float4(0.f, 0.f, 0.f, 0.f);
        o4[i * 4 + 0] = z; o4[i * 4 + 1] = z; o4[i * 4 + 2] = z; o4[i * 4 + 3] = z;
    }
}

// ---------------------------------------------------------------- kmax ----
// 384 blocks: rb = b>>6 (6 row-blocks of 2048), jc = b&63 (192 j's each)
__global__ __launch_bounds__(256) void kmax_kernel(const float* __restrict__ x,
                                                   const float4* __restrict__ y4,
                                                   unsigned* __restrict__ G) {
    __shared__ float s0[192], s1[192], s2[192], sw[192];
    int t  = threadIdx.x;
    int rb = blockIdx.x >> 6;
    int jc = blockIdx.x & 63;
    int j0 = jc * 192;
    if (t < 192) {
        float4 v = y4[j0 + t];
        s0[t] = v.x; s1[t] = v.y; s2[t] = v.z; sw[t] = v.w;
    }
    __syncthreads();

    int wv   = t >> 6;
    int lane = t & 63;
    int r0   = rb * 2048 + wv * 512 + lane;   // rows r0 + 64k, k=0..7

    float X0[8], X1[8], X2[8];
    f32x2 mk[8];
    #pragma unroll
    for (int k = 0; k < 8; ++k) {
        int row = r0 + 64 * k;
        X0[k] = x[3 * row + 0]; X1[k] = x[3 * row + 1]; X2[k] = x[3 * row + 2];
        mk[k] = sp2(-3.4e38f);
    }

    for (int jj = 0; jj < 192; jj += 4) {
        f32x4 a0 = *(const f32x4*)&s0[jj];
        f32x4 a1 = *(const f32x4*)&s1[jj];
        f32x4 a2 = *(const f32x4*)&s2[jj];
        f32x4 aw = *(const f32x4*)&sw[jj];
        #pragma unroll
        for (int k = 0; k < 8; ++k) {
            f32x2 g = fma2(sp2(X2[k]), a2.xy, aw.xy);
            g = fma2(sp2(X1[k]), a1.xy, g);
            g = fma2(sp2(X0[k]), a0.xy, g);
            mk[k] = max2(mk[k], g);
            f32x2 h = fma2(sp2(X2[k]), a2.zw, aw.zw);
            h = fma2(sp2(X1[k]), a1.zw, h);
            h = fma2(sp2(X0[k]), a0.zw, h);
            mk[k] = max2(mk[k], h);
        }
    }
    #pragma unroll
    for (int k = 0; k < 8; ++k)
        atomicMax(G + r0 + 64 * k, enc_f(fmaxf(mk[k].x, mk[k].y)));
}

// ---------------------------------------------------------------- kacc ----
// 1536 blocks x 256 threads: rb = b>>5 (48 row-blocks of 256 rows),
// jc = b&31 (384 j's each = 12 MFMA k-tiles). Fb fragments read from global
// (L2-resident, coalesced 16B/lane); only Y SoA staged in LDS (6 KB).
__global__ __launch_bounds__(256, 4) void kacc_kernel(const float* __restrict__ x,
                                                      const float4* __restrict__ y4,
                                                      const uint4* __restrict__ feaB,
                                                      const unsigned* __restrict__ G,
                                                      float* __restrict__ ssum,
                                                      float* __restrict__ out) {
    __shared__ float Ys0[384], Ys1[384], Ys2[384], Ysw[384];  // 6 KB SoA
    int t  = threadIdx.x;
    int rb = blockIdx.x >> 5;
    int jc = blockIdx.x & 31;
    int j0 = jc * 384;

    for (int i = t; i < 384; i += 256) {
        float4 v = y4[j0 + i];
        Ys0[i] = v.x; Ys1[i] = v.y; Ys2[i] = v.z; Ysw[i] = v.w;
    }
    __syncthreads();

    int wv   = t >> 6;
    int lane = t & 63;
    int grp  = lane >> 4;
    int m    = lane & 15;
    int rowbase = rb * 256 + wv * 64;

    float X0[4], X1[4], X2[4], Gm[4];
    #pragma unroll
    for (int r = 0; r < 4; ++r) {
        int row = rowbase + r * 16 + m;
        X0[r] = x[3 * row + 0]; X1[r] = x[3 * row + 1]; X2[r] = x[3 * row + 2];
        Gm[r] = dec_f(G[row]);
    }

    const uint4* fb = feaB + jc * 768 + lane;   // + kt*64 per tile

    const bf16x8 ones = (bf16x8){(short)0x3F80, (short)0x3F80, (short)0x3F80, (short)0x3F80,
                                 (short)0x3F80, (short)0x3F80, (short)0x3F80, (short)0x3F80};
    f32x4 acc[4], accs[4];
    #pragma unroll
    for (int r = 0; r < 4; ++r) {
        acc[r]  = (f32x4){0.f, 0.f, 0.f, 0.f};
        accs[r] = (f32x4){0.f, 0.f, 0.f, 0.f};
    }

    for (int kt = 0; kt < 12; ++kt) {
        int jb = kt * 32 + grp * 8;   // this lane's 8 k-positions
        f32x4 A0 = *(const f32x4*)&Ys0[jb], B0 = *(const f32x4*)&Ys0[jb + 4];
        f32x4 A1 = *(const f32x4*)&Ys1[jb], B1 = *(const f32x4*)&Ys1[jb + 4];
        f32x4 A2 = *(const f32x4*)&Ys2[jb], B2 = *(const f32x4*)&Ys2[jb + 4];
        f32x4 Aw = *(const f32x4*)&Ysw[jb], Bw = *(const f32x4*)&Ysw[jb + 4];
        bf16x8 bfrag = __builtin_bit_cast(bf16x8, fb[kt * 64]);

        #pragma unroll
        for (int r = 0; r < 4; ++r) {
            f32x2 x0 = sp2(X0[r]), x1 = sp2(X1[r]), x2 = sp2(X2[r]);
            f32x2 gm = sp2(Gm[r]);
            f32x2 g0 = fma2(x0, A0.xy, fma2(x1, A1.xy, fma2(x2, A2.xy, Aw.xy))) - gm;
            f32x2 g1 = fma2(x0, A0.zw, fma2(x1, A1.zw, fma2(x2, A2.zw, Aw.zw))) - gm;
            f32x2 g2 = fma2(x0, B0.xy, fma2(x1, B1.xy, fma2(x2, B2.xy, Bw.xy))) - gm;
            f32x2 g3 = fma2(x0, B0.zw, fma2(x1, B1.zw, fma2(x2, B2.zw, Bw.zw))) - gm;
            union { unsigned u[4]; bf16x8 v; } af;
            af.u[0] = pk_bf16(EXP2(g0.x), EXP2(g0.y));
            af.u[1] = pk_bf16(EXP2(g1.x), EXP2(g1.y));
            af.u[2] = pk_bf16(EXP2(g2.x), EXP2(g2.y));
            af.u[3] = pk_bf16(EXP2(g3.x), EXP2(g3.y));
            acc[r]  = __builtin_amdgcn_mfma_f32_16x16x32_bf16(af.v, bfrag, acc[r], 0, 0, 0);
            accs[r] = __builtin_amdgcn_mfma_f32_16x16x32_bf16(af.v, ones,  accs[r], 0, 0, 0);
        }
    }

    // epilogue. C/D layout: lane (grp,m) holds D[grp*4+reg][m].
    #pragma unroll
    for (int r = 0; r < 4; ++r) {
        #pragma unroll
        for (int reg = 0; reg < 4; ++reg) {
            int orow = rowbase + r * 16 + grp * 4 + reg;
            atomicAdd(out + (size_t)orow * DFEA + m, acc[r][reg]);
        }
        if (m == 0) {
            #pragma unroll
            for (int reg = 0; reg < 4; ++reg)
                atomicAdd(ssum + rowbase + r * 16 + grp * 4 + reg, accs[r][reg]);
        }
    }
}

// ---------------------------------------------------------------- kdiv ----
__global__ __launch_bounds__(256) void kdiv_kernel(float* __restrict__ out,
                                                   const float* __restrict__ ssum) {
    int t = blockIdx.x * 256 + threadIdx.x;
    out[t] = out[t] / ssum[t >> 4];   // s >= 1 (arg==0 at the argmax j)
}

// -------------------------------------------------------------- launch ----
extern "C" void kernel_launch(void* const* d_in, const int* in_sizes, int n_in,
                              void* d_out, int out_size, void* d_ws, size_t ws_size,
                              hipStream_t stream) {
    const float* x   = (const float*)d_in[0];   // [N,3]
    const float* y   = (const float*)d_in[1];   // [M,3]
    const float* fea = (const float*)d_in[2];   // [M,16]
    float* out = (float*)d_out;                 // [N,16]

    float*    wsf  = (float*)d_ws;
    unsigned* G    = (unsigned*)wsf;                        // N u32 (enc, 0 = -inf)
    float*    ssum = wsf + NROWS;                           // N f32
    float4*   y4   = (float4*)(wsf + 2 * NROWS);            // N float4
    uint4*    feaB = (uint4*)(wsf + 6 * NROWS);             // 2N uint4

    kprep_kernel<<<dim3(192), 256, 0, stream>>>(y, fea, y4, feaB, G, ssum, out);
    kmax_kernel<<<dim3(6 * 64), 256, 0, stream>>>(x, y4, G);
    kacc_kernel<<<dim3(48 * 32), 256, 0, stream>>>(x, y4, feaB, G, ssum, out);
    kdiv_kernel<<<dim3((NROWS * DFEA) / 256), 256, 0, stream>>>(out, ssum);
}